// Round 1
// baseline (441.917 us; speedup 1.0000x reference)
//
#include <hip/hip_runtime.h>
#include <hip/hip_bf16.h>

#define NT   8
#define INF  128
#define OUTF 64

typedef __attribute__((ext_vector_type(8))) short short8;   // 8 bf16 (4 VGPRs) — MFMA A/B frag
typedef __attribute__((ext_vector_type(4))) float f32x4;    // MFMA C/D frag

__device__ __forceinline__ short f2bf(float f) {
  __hip_bfloat16 h = __float2bfloat16(f);
  return __builtin_bit_cast(short, h);
}

// ---- workspace layout (as int*) ----
// ws[0..7]   histogram
// ws[8..16]  start[9] (exclusive prefix; start[8] = N)
// ws[24..31] scatter cursors
// ws[32..]   perm[N] (nodes sorted by type)

__global__ void hl_hist(const int* __restrict__ nt, int* __restrict__ ws, int N) {
  __shared__ int bins[NT];
  if (threadIdx.x < NT) bins[threadIdx.x] = 0;
  __syncthreads();
  const int N4 = N >> 2;
  const int4* p = (const int4*)nt;
  for (int i = blockIdx.x * blockDim.x + threadIdx.x; i < N4; i += gridDim.x * blockDim.x) {
    int4 v = p[i];
    atomicAdd(&bins[v.x], 1); atomicAdd(&bins[v.y], 1);
    atomicAdd(&bins[v.z], 1); atomicAdd(&bins[v.w], 1);
  }
  if (blockIdx.x == 0 && threadIdx.x < (N & 3))
    atomicAdd(&bins[nt[N4 * 4 + threadIdx.x]], 1);
  __syncthreads();
  if (threadIdx.x < NT) atomicAdd(&ws[threadIdx.x], bins[threadIdx.x]);
}

__global__ void hl_prefix(int* __restrict__ ws) {
  if (threadIdx.x == 0) {
    int s = 0;
    for (int t = 0; t < NT; ++t) { ws[8 + t] = s; ws[24 + t] = s; s += ws[t]; }
    ws[16] = s;
  }
}

#define SCHUNK 2048
__global__ void hl_scatter(const int* __restrict__ nt, int* __restrict__ ws, int N) {
  __shared__ int bins[NT], base[NT];
  int* cursor = ws + 24;
  int* perm   = ws + 32;
  if (threadIdx.x < NT) bins[threadIdx.x] = 0;
  __syncthreads();
  const int n0 = blockIdx.x * SCHUNK + threadIdx.x * 8;
  int ty[8], rk[8];
  #pragma unroll
  for (int i = 0; i < 8; ++i) {
    int n = n0 + i;
    if (n < N) { int t = nt[n]; ty[i] = t; rk[i] = atomicAdd(&bins[t], 1); }
    else ty[i] = -1;
  }
  __syncthreads();
  if (threadIdx.x < NT) base[threadIdx.x] = atomicAdd(&cursor[threadIdx.x], bins[threadIdx.x]);
  __syncthreads();
  #pragma unroll
  for (int i = 0; i < 8; ++i)
    if (ty[i] >= 0) perm[base[ty[i]] + rk[i]] = n0 + i;
}

// GEMM over type-sorted rows. blockIdx.y = type. 4 waves/block, each wave owns
// 16-row tiles (16x16x32 bf16 MFMA, 4 col-blocks x 4 k-steps = 16 MFMA/tile).
// W[t] frags held in registers (64 VGPRs), loaded once per wave, reused across
// the grid-stride tile loop. No LDS, no __syncthreads.
__global__ __launch_bounds__(256) void hl_gemm(
    const float* __restrict__ x, const float* __restrict__ W,
    const float* __restrict__ b, const int* __restrict__ ws,
    float* __restrict__ out) {
  const int* start = ws + 8;
  const int* perm  = ws + 32;
  const int t  = blockIdx.y;
  const int s0 = start[t], s1 = start[t + 1];
  const int count = s1 - s0;
  if (count <= 0) return;
  const int ntiles = (count + 15) >> 4;
  if ((int)(blockIdx.x * 4) >= ntiles) return;   // whole block idle

  const int wave = threadIdx.x >> 6;
  const int lane = threadIdx.x & 63;
  const int q = lane >> 4, c = lane & 15;

  // B frags: B[k = s*32 + q*8 + j][col = nb*16 + c]
  short8 wf[4][4];
  const float* Wt = W + t * INF * OUTF;
  #pragma unroll
  for (int s = 0; s < 4; ++s)
    #pragma unroll
    for (int nb = 0; nb < 4; ++nb) {
      short8 v;
      #pragma unroll
      for (int j = 0; j < 8; ++j)
        v[j] = f2bf(Wt[(s * 32 + q * 8 + j) * OUTF + nb * 16 + c]);
      wf[s][nb] = v;
    }
  float bias[4];
  #pragma unroll
  for (int nb = 0; nb < 4; ++nb) bias[nb] = b[t * OUTF + nb * 16 + c];

  for (int tile = blockIdx.x * 4 + wave; tile < ntiles; tile += gridDim.x * 4) {
    const int rowbase = s0 + tile * 16;
    int ra = rowbase + c; if (ra > s1 - 1) ra = s1 - 1;   // clamp; masked at store
    const int na = perm[ra];
    const float* xr = x + (long)na * INF;
    // A frag: A[m = c][k = s*32 + q*8 + j] — 8 consecutive floats per (s,lane)
    f32x4 xv[4][2];
    #pragma unroll
    for (int s = 0; s < 4; ++s) {
      xv[s][0] = *(const f32x4*)(xr + s * 32 + q * 8);
      xv[s][1] = *(const f32x4*)(xr + s * 32 + q * 8 + 4);
    }
    short8 af[4];
    #pragma unroll
    for (int s = 0; s < 4; ++s)
      #pragma unroll
      for (int j = 0; j < 4; ++j) {
        af[s][j]     = f2bf(xv[s][0][j]);
        af[s][j + 4] = f2bf(xv[s][1][j]);
      }
    f32x4 acc[4] = {{0,0,0,0},{0,0,0,0},{0,0,0,0},{0,0,0,0}};
    #pragma unroll
    for (int s = 0; s < 4; ++s)
      #pragma unroll
      for (int nb = 0; nb < 4; ++nb)
        acc[nb] = __builtin_amdgcn_mfma_f32_16x16x32_bf16(af[s], wf[s][nb], acc[nb], 0, 0, 0);
    // C/D layout: col = lane&15, row = q*4 + reg (verified m89/m91)
    const int rb = rowbase + q * 4;
    #pragma unroll
    for (int r = 0; r < 4; ++r) {
      const int rowi = rb + r;
      if (rowi < s1) {
        const int node = perm[rowi];
        float* orow = out + (long)node * OUTF + c;
        #pragma unroll
        for (int nb = 0; nb < 4; ++nb)
          orow[nb * 16] = acc[nb][r] + bias[nb];
      }
    }
  }
}

extern "C" void kernel_launch(void* const* d_in, const int* in_sizes, int n_in,
                              void* d_out, int out_size, void* d_ws, size_t ws_size,
                              hipStream_t stream) {
  const float* x  = (const float*)d_in[0];
  const int*   nt = (const int*)d_in[1];
  const float* W  = (const float*)d_in[2];
  const float* b  = (const float*)d_in[3];
  float* out = (float*)d_out;
  const int N = in_sizes[1];
  int* ws = (int*)d_ws;

  // zero histogram region only (ws re-poisoned 0xAA before every call)
  hipMemsetAsync(ws, 0, 32 * sizeof(int), stream);
  hl_hist<<<256, 256, 0, stream>>>(nt, ws, N);
  hl_prefix<<<1, 64, 0, stream>>>(ws);
  hl_scatter<<<(N + SCHUNK - 1) / SCHUNK, 256, 0, stream>>>(nt, ws, N);
  dim3 grid(128, NT);
  hl_gemm<<<grid, 256, 0, stream>>>(x, W, b, ws, out);
}